// Round 1
// baseline (517.288 us; speedup 1.0000x reference)
//
#include <hip/hip_runtime.h>

#define IH 256
#define IW 256
#define FH 128
#define FW 128
#define NB 16
#define ICH 33
#define NF 10
#define NC 30          // warped channels = NF*3
#define SPLIT 8        // blocks per (b,c) in kernel A
#define PIX_PER_BLOCK ((FH * FW) / SPLIT)

// align-corners bilinear sample of the 256x256 plane at integer 128-grid point (Y,X)
__device__ __forceinline__ float resized_at(const float* __restrict__ plane, int Y, int X) {
    const float s = (float)(255.0 / 127.0);   // matches jax f32 scale
    float fy = (float)Y * s;
    float fx = (float)X * s;
    int y0 = (int)fy; y0 = y0 > IH - 2 ? IH - 2 : y0;
    int x0 = (int)fx; x0 = x0 > IW - 2 ? IW - 2 : x0;
    float wy = fy - (float)y0;
    float wx = fx - (float)x0;
    const float* p0 = plane + y0 * IW + x0;
    float v00 = p0[0], v01 = p0[1];
    float v10 = p0[IW], v11 = p0[IW + 1];
    float r0 = v00 * (1.f - wy) + v10 * wy;   // rows = img[y0]*(1-wy)+img[y1]*wy
    float r1 = v01 * (1.f - wy) + v11 * wy;
    return r0 * (1.f - wx) + r1 * wx;          // out = rows[x0]*(1-wx)+rows[x1]*wx
}

__device__ __forceinline__ float charb(float g) {
    return powf(g * g + 1e-6f, 0.4f);
}

// Kernel A: warp + per-(b,c) SSIM sums + pixel Charbonnier sum
__global__ void __launch_bounds__(256) loss_main(const float* __restrict__ images,
                                                 const float* __restrict__ flows,
                                                 float* __restrict__ acc_bc,   // [480][8]
                                                 float* __restrict__ acc_g)    // [4]
{
    int bc = blockIdx.x / SPLIT;
    int part = blockIdx.x % SPLIT;
    int b = bc / NC;
    int c = bc % NC;
    int f = c / 3;
    const float* ref_plane = images + (size_t)(b * ICH + c) * (IH * IW);
    const float* src_plane = images + (size_t)(b * ICH + 3 + c) * (IH * IW);
    const float* fx_plane  = flows + (size_t)(b * 2 * NF + 2 * f) * (FH * FW);
    const float* fy_plane  = fx_plane + FH * FW;

    float s_ref = 0.f, s_w = 0.f, s_r2 = 0.f, s_w2 = 0.f, s_rw = 0.f, s_pix = 0.f;
    int base = part * PIX_PER_BLOCK;
    for (int i = threadIdx.x; i < PIX_PER_BLOCK; i += 256) {
        int pix = base + i;
        int h = pix >> 7;
        int w = pix & (FW - 1);
        float ref = resized_at(ref_plane, h, w);

        float fxv = fx_plane[pix];
        float fyv = fy_plane[pix];
        float gx = (float)w + fxv;
        float gy = (float)h + fyv;
        float x0f = floorf(gx), y0f = floorf(gy);
        float wx = gx - x0f, wy = gy - y0f;
        int x0 = (int)x0f; x0 = min(max(x0, 0), FW - 1);
        int y0 = (int)y0f; y0 = min(max(y0, 0), FH - 1);
        int x1 = min(x0 + 1, FW - 1);
        int y1 = min(y0 + 1, FH - 1);
        float v00 = resized_at(src_plane, y0, x0);
        float v01 = resized_at(src_plane, y0, x1);
        float v10 = resized_at(src_plane, y1, x0);
        float v11 = resized_at(src_plane, y1, x1);
        float top = v00 * (1.f - wx) + v01 * wx;
        float bot = v10 * (1.f - wx) + v11 * wx;
        float wv = top * (1.f - wy) + bot * wy;

        s_ref += ref; s_w += wv;
        s_r2 += ref * ref; s_w2 += wv * wv; s_rw += ref * wv;
        float d = ref - wv;
        s_pix += charb(d);
    }
    // wave64 shuffle reduction
    for (int off = 32; off > 0; off >>= 1) {
        s_ref += __shfl_down(s_ref, off, 64);
        s_w   += __shfl_down(s_w, off, 64);
        s_r2  += __shfl_down(s_r2, off, 64);
        s_w2  += __shfl_down(s_w2, off, 64);
        s_rw  += __shfl_down(s_rw, off, 64);
        s_pix += __shfl_down(s_pix, off, 64);
    }
    if ((threadIdx.x & 63) == 0) {
        float* a = acc_bc + bc * 8;
        atomicAdd(a + 0, s_ref);
        atomicAdd(a + 1, s_w);
        atomicAdd(a + 2, s_r2);
        atomicAdd(a + 3, s_w2);
        atomicAdd(a + 4, s_rw);
        atomicAdd(acc_g + 0, s_pix);
    }
}

// Kernel B: smoothness term. torch_gradient along axis 1 (flow index!) and axis 2 (H).
__global__ void __launch_bounds__(256) smooth_kernel(const float* __restrict__ flows,
                                                     float* __restrict__ acc_g)
{
    const int total = NB * NF * FH * FW;
    const int PL = FH * FW;       // plane size
    float s = 0.f;
    for (int i = blockIdx.x * blockDim.x + threadIdx.x; i < total;
         i += gridDim.x * blockDim.x) {
        int w = i & (FW - 1);
        int h = (i >> 7) & (FH - 1);
        int f = (i >> 14) % NF;
        int b = i / (NF * FH * FW);
        int pix = h * FW + w;
        const float* xp = flows + (size_t)(b * 2 * NF + 2 * f) * PL;
        const float* yp = xp + PL;

        float g1x, g1y;   // gradient along flow-channel axis (stride 2 planes)
        if (f == 0)           { g1x = xp[2 * PL + pix] - xp[pix];
                                g1y = yp[2 * PL + pix] - yp[pix]; }
        else if (f == NF - 1) { g1x = xp[pix] - xp[pix - 2 * PL];
                                g1y = yp[pix] - yp[pix - 2 * PL]; }
        else                  { g1x = 0.5f * (xp[2 * PL + pix] - xp[pix - 2 * PL]);
                                g1y = 0.5f * (yp[2 * PL + pix] - yp[pix - 2 * PL]); }

        float g2x, g2y;   // gradient along H
        if (h == 0)           { g2x = xp[pix + FW] - xp[pix];
                                g2y = yp[pix + FW] - yp[pix]; }
        else if (h == FH - 1) { g2x = xp[pix] - xp[pix - FW];
                                g2y = yp[pix] - yp[pix - FW]; }
        else                  { g2x = 0.5f * (xp[pix + FW] - xp[pix - FW]);
                                g2y = 0.5f * (yp[pix + FW] - yp[pix - FW]); }

        s += charb(g1x) + charb(g2x) + charb(g1y) + charb(g2y);
    }
    for (int off = 32; off > 0; off >>= 1) s += __shfl_down(s, off, 64);
    if ((threadIdx.x & 63) == 0) atomicAdd(acc_g + 2, s);
}

// Kernel C: per-(b,c) SSIM from sums, then combine everything into the scalar
__global__ void __launch_bounds__(512) finalize(const float* __restrict__ acc_bc,
                                                const float* __restrict__ acc_g,
                                                float* __restrict__ out)
{
    __shared__ float sh[512];
    int tid = threadIdx.x;
    float ssim = 0.f;
    if (tid < NB * NC) {
        const float* a = acc_bc + tid * 8;
        const float N = (float)(FH * FW);
        float mu1 = a[0] / N, mu2 = a[1] / N;
        float var1 = (a[2] - a[0] * mu1) / (N - 1.f);
        float var2 = (a[3] - a[1] * mu2) / (N - 1.f);
        float s12 = a[4] / N - mu1 * mu2;
        float num = (2.f * mu1 * mu2 + 1e-4f) * (2.f * s12 + 1e-3f);
        float den = (mu1 * mu1 + mu2 * mu2 + 1e-4f) * (var1 + var2 + 1e-3f);
        ssim = num / den;
    }
    sh[tid] = ssim;
    __syncthreads();
    for (int off = 256; off > 0; off >>= 1) {
        if (tid < off) sh[tid] += sh[tid + off];
        __syncthreads();
    }
    if (tid == 0) {
        float pix    = acc_g[0] / (float)(NB * NC * FH * FW);
        float smooth = acc_g[2] / (float)(NB * NF * FH * FW);
        float sim    = sh[0] / (float)(NB * NC);
        out[0] = pix + 0.01f * smooth + sim;
    }
}

extern "C" void kernel_launch(void* const* d_in, const int* in_sizes, int n_in,
                              void* d_out, int out_size, void* d_ws, size_t ws_size,
                              hipStream_t stream) {
    const float* images = (const float*)d_in[0];
    const float* flows  = (const float*)d_in[1];
    float* acc_bc = (float*)d_ws;              // 480*8 floats
    float* acc_g  = acc_bc + NB * NC * 8;      // 4 floats
    hipMemsetAsync(d_ws, 0, (NB * NC * 8 + 4) * sizeof(float), stream);
    loss_main<<<NB * NC * SPLIT, 256, 0, stream>>>(images, flows, acc_bc, acc_g);
    smooth_kernel<<<2560, 256, 0, stream>>>(flows, acc_g);
    finalize<<<1, 512, 0, stream>>>(acc_bc, acc_g, (float*)d_out);
}

// Round 3
// 277.522 us; speedup vs baseline: 1.8640x; 1.8640x over previous
//
#include <hip/hip_runtime.h>

#define IH 256
#define IW 256
#define FH 128
#define FW 128
#define NB 16
#define ICH 33
#define NF 10
#define NC 30          // warped channels = NF*3
#define PL (FH * FW)   // 16384
#define RES_OFF 4096                       // floats: acc region + pad
#define RES_CNT (NB * ICH * PL)            // 8,650,752 floats
#define WS_NEED ((size_t)(RES_OFF + RES_CNT) * 4)

// fast exact charbonnier: (g^2 + 1e-6)^0.4, arg always > 0 so fast log/exp safe.
// __builtin_amdgcn_logf = v_log_f32 (log2), __builtin_amdgcn_exp2f = v_exp_f32 (2^x)
__device__ __forceinline__ float charb(float g) {
    float t = fmaf(g, g, 1e-6f);
    return __builtin_amdgcn_exp2f(0.4f * __builtin_amdgcn_logf(t));
}

// align-corners bilinear sample of a 256x256 plane at 128-grid point (Y,X)
__device__ __forceinline__ float resized_at(const float* __restrict__ plane, int Y, int X) {
    const float s = (float)(255.0 / 127.0);
    float fy = (float)Y * s;
    float fx = (float)X * s;
    int y0 = (int)fy; y0 = y0 > IH - 2 ? IH - 2 : y0;
    int x0 = (int)fx; x0 = x0 > IW - 2 ? IW - 2 : x0;
    float wy = fy - (float)y0;
    float wx = fx - (float)x0;
    const float* p0 = plane + y0 * IW + x0;
    float v00 = p0[0], v01 = p0[1];
    float v10 = p0[IW], v11 = p0[IW + 1];
    float r0 = v00 * (1.f - wy) + v10 * wy;
    float r1 = v01 * (1.f - wy) + v11 * wy;
    return r0 * (1.f - wx) + r1 * wx;
}

// ---- Kernel R: materialize resized images (all 33 channels) into ws ----
__global__ void __launch_bounds__(256) resize_kernel(const float* __restrict__ images,
                                                     float* __restrict__ resized)
{
    int idx = blockIdx.x * 256 + threadIdx.x;          // over NB*ICH*PL
    int bc = idx >> 14;
    int pix = idx & (PL - 1);
    int h = pix >> 7;
    int w = pix & (FW - 1);
    const float* plane = images + (size_t)bc * (IH * IW);
    resized[idx] = resized_at(plane, h, w);
}

// ---- Kernel A: warp + SSIM sums + pixel Charbonnier, from materialized resize ----
#define SPLIT 4
#define PIX_PER_BLOCK (PL / SPLIT)
__global__ void __launch_bounds__(256) loss_main(const float* __restrict__ resized,
                                                 const float* __restrict__ flows,
                                                 float* __restrict__ acc_bc,   // [480][8]
                                                 float* __restrict__ acc_g)    // [4]
{
    int bc = blockIdx.x / SPLIT;
    int part = blockIdx.x % SPLIT;
    int b = bc / NC;
    int c = bc % NC;
    int f = c / 3;
    const float* ref_plane = resized + (size_t)(b * ICH + c) * PL;
    const float* src_plane = resized + (size_t)(b * ICH + 3 + c) * PL;
    const float* fx_plane  = flows + (size_t)(b * 2 * NF + 2 * f) * PL;
    const float* fy_plane  = fx_plane + PL;

    float s_ref = 0.f, s_w = 0.f, s_r2 = 0.f, s_w2 = 0.f, s_rw = 0.f, s_pix = 0.f;
    int base = part * PIX_PER_BLOCK;
    for (int i = threadIdx.x; i < PIX_PER_BLOCK; i += 256) {
        int pix = base + i;
        int h = pix >> 7;
        int w = pix & (FW - 1);
        float ref = ref_plane[pix];
        float fxv = fx_plane[pix];
        float fyv = fy_plane[pix];
        float gx = (float)w + fxv;
        float gy = (float)h + fyv;
        float x0f = floorf(gx), y0f = floorf(gy);
        float wx = gx - x0f, wy = gy - y0f;
        int x0 = (int)x0f; x0 = min(max(x0, 0), FW - 1);
        int y0 = (int)y0f; y0 = min(max(y0, 0), FH - 1);
        int x1 = min(x0 + 1, FW - 1);
        int y1 = min(y0 + 1, FH - 1);
        const float* r0p = src_plane + y0 * FW;
        const float* r1p = src_plane + y1 * FW;
        float v00 = r0p[x0], v01 = r0p[x1];
        float v10 = r1p[x0], v11 = r1p[x1];
        float top = v00 * (1.f - wx) + v01 * wx;
        float bot = v10 * (1.f - wx) + v11 * wx;
        float wv = top * (1.f - wy) + bot * wy;

        s_ref += ref; s_w += wv;
        s_r2 += ref * ref; s_w2 += wv * wv; s_rw += ref * wv;
        s_pix += charb(ref - wv);
    }
    // wave64 shuffle reduction
    for (int off = 32; off > 0; off >>= 1) {
        s_ref += __shfl_down(s_ref, off, 64);
        s_w   += __shfl_down(s_w, off, 64);
        s_r2  += __shfl_down(s_r2, off, 64);
        s_w2  += __shfl_down(s_w2, off, 64);
        s_rw  += __shfl_down(s_rw, off, 64);
        s_pix += __shfl_down(s_pix, off, 64);
    }
    __shared__ float sh[4][6];
    int wave = threadIdx.x >> 6;
    if ((threadIdx.x & 63) == 0) {
        sh[wave][0] = s_ref; sh[wave][1] = s_w; sh[wave][2] = s_r2;
        sh[wave][3] = s_w2;  sh[wave][4] = s_rw; sh[wave][5] = s_pix;
    }
    __syncthreads();
    if (threadIdx.x == 0) {
        float t0 = 0, t1 = 0, t2 = 0, t3 = 0, t4 = 0, t5 = 0;
        for (int v = 0; v < 4; v++) {
            t0 += sh[v][0]; t1 += sh[v][1]; t2 += sh[v][2];
            t3 += sh[v][3]; t4 += sh[v][4]; t5 += sh[v][5];
        }
        float* a = acc_bc + bc * 8;
        atomicAdd(a + 0, t0);
        atomicAdd(a + 1, t1);
        atomicAdd(a + 2, t2);
        atomicAdd(a + 3, t3);
        atomicAdd(a + 4, t4);
        atomicAdd(acc_g + 0, t5);
    }
}

// ---- Kernel B: smoothness. gradient along flow-index axis and H axis ----
__global__ void __launch_bounds__(256) smooth_kernel(const float* __restrict__ flows,
                                                     float* __restrict__ acc_g)
{
    const int total = NB * NF * PL;
    float s = 0.f;
    for (int i = blockIdx.x * blockDim.x + threadIdx.x; i < total;
         i += gridDim.x * blockDim.x) {
        int w = i & (FW - 1);
        int h = (i >> 7) & (FH - 1);
        int f = (i >> 14) % NF;
        int b = i / (NF * PL);
        int pix = h * FW + w;
        const float* xp = flows + (size_t)(b * 2 * NF + 2 * f) * PL;
        const float* yp = xp + PL;

        float g1x, g1y;   // gradient along flow-channel axis (stride 2 planes)
        if (f == 0)           { g1x = xp[2 * PL + pix] - xp[pix];
                                g1y = yp[2 * PL + pix] - yp[pix]; }
        else if (f == NF - 1) { g1x = xp[pix] - xp[pix - 2 * PL];
                                g1y = yp[pix] - yp[pix - 2 * PL]; }
        else                  { g1x = 0.5f * (xp[2 * PL + pix] - xp[pix - 2 * PL]);
                                g1y = 0.5f * (yp[2 * PL + pix] - yp[pix - 2 * PL]); }

        float g2x, g2y;   // gradient along H
        if (h == 0)           { g2x = xp[pix + FW] - xp[pix];
                                g2y = yp[pix + FW] - yp[pix]; }
        else if (h == FH - 1) { g2x = xp[pix] - xp[pix - FW];
                                g2y = yp[pix] - yp[pix - FW]; }
        else                  { g2x = 0.5f * (xp[pix + FW] - xp[pix - FW]);
                                g2y = 0.5f * (yp[pix + FW] - yp[pix - FW]); }

        s += charb(g1x) + charb(g2x) + charb(g1y) + charb(g2y);
    }
    for (int off = 32; off > 0; off >>= 1) s += __shfl_down(s, off, 64);
    __shared__ float sh[4];
    int wave = threadIdx.x >> 6;
    if ((threadIdx.x & 63) == 0) sh[wave] = s;
    __syncthreads();
    if (threadIdx.x == 0)
        atomicAdd(acc_g + 2, sh[0] + sh[1] + sh[2] + sh[3]);
}

// ---- Kernel C: per-(b,c) SSIM + final scalar ----
__global__ void __launch_bounds__(512) finalize(const float* __restrict__ acc_bc,
                                                const float* __restrict__ acc_g,
                                                float* __restrict__ out)
{
    __shared__ float sh[512];
    int tid = threadIdx.x;
    float ssim = 0.f;
    if (tid < NB * NC) {
        const float* a = acc_bc + tid * 8;
        const float N = (float)PL;
        float mu1 = a[0] / N, mu2 = a[1] / N;
        float var1 = (a[2] - a[0] * mu1) / (N - 1.f);
        float var2 = (a[3] - a[1] * mu2) / (N - 1.f);
        float s12 = a[4] / N - mu1 * mu2;
        float num = (2.f * mu1 * mu2 + 1e-4f) * (2.f * s12 + 1e-3f);
        float den = (mu1 * mu1 + mu2 * mu2 + 1e-4f) * (var1 + var2 + 1e-3f);
        ssim = num / den;
    }
    sh[tid] = ssim;
    __syncthreads();
    for (int off = 256; off > 0; off >>= 1) {
        if (tid < off) sh[tid] += sh[tid + off];
        __syncthreads();
    }
    if (tid == 0) {
        float pix    = acc_g[0] / (float)(NB * NC * PL);
        float smooth = acc_g[2] / (float)(NB * NF * PL);
        float sim    = sh[0] / (float)(NB * NC);
        out[0] = pix + 0.01f * smooth + sim;
    }
}

// ---- Fallback kernel (round-1 structure) if ws too small to materialize ----
__global__ void __launch_bounds__(256) loss_main_fb(const float* __restrict__ images,
                                                    const float* __restrict__ flows,
                                                    float* __restrict__ acc_bc,
                                                    float* __restrict__ acc_g)
{
    int bc = blockIdx.x / 8;
    int part = blockIdx.x % 8;
    int b = bc / NC;
    int c = bc % NC;
    int f = c / 3;
    const float* ref_plane = images + (size_t)(b * ICH + c) * (IH * IW);
    const float* src_plane = images + (size_t)(b * ICH + 3 + c) * (IH * IW);
    const float* fx_plane  = flows + (size_t)(b * 2 * NF + 2 * f) * PL;
    const float* fy_plane  = fx_plane + PL;

    float s_ref = 0.f, s_w = 0.f, s_r2 = 0.f, s_w2 = 0.f, s_rw = 0.f, s_pix = 0.f;
    int base = part * (PL / 8);
    for (int i = threadIdx.x; i < PL / 8; i += 256) {
        int pix = base + i;
        int h = pix >> 7;
        int w = pix & (FW - 1);
        float ref = resized_at(ref_plane, h, w);
        float fxv = fx_plane[pix];
        float fyv = fy_plane[pix];
        float gx = (float)w + fxv;
        float gy = (float)h + fyv;
        float x0f = floorf(gx), y0f = floorf(gy);
        float wx = gx - x0f, wy = gy - y0f;
        int x0 = (int)x0f; x0 = min(max(x0, 0), FW - 1);
        int y0 = (int)y0f; y0 = min(max(y0, 0), FH - 1);
        int x1 = min(x0 + 1, FW - 1);
        int y1 = min(y0 + 1, FH - 1);
        float v00 = resized_at(src_plane, y0, x0);
        float v01 = resized_at(src_plane, y0, x1);
        float v10 = resized_at(src_plane, y1, x0);
        float v11 = resized_at(src_plane, y1, x1);
        float top = v00 * (1.f - wx) + v01 * wx;
        float bot = v10 * (1.f - wx) + v11 * wx;
        float wv = top * (1.f - wy) + bot * wy;
        s_ref += ref; s_w += wv;
        s_r2 += ref * ref; s_w2 += wv * wv; s_rw += ref * wv;
        s_pix += charb(ref - wv);
    }
    for (int off = 32; off > 0; off >>= 1) {
        s_ref += __shfl_down(s_ref, off, 64);
        s_w   += __shfl_down(s_w, off, 64);
        s_r2  += __shfl_down(s_r2, off, 64);
        s_w2  += __shfl_down(s_w2, off, 64);
        s_rw  += __shfl_down(s_rw, off, 64);
        s_pix += __shfl_down(s_pix, off, 64);
    }
    if ((threadIdx.x & 63) == 0) {
        float* a = acc_bc + bc * 8;
        atomicAdd(a + 0, s_ref);
        atomicAdd(a + 1, s_w);
        atomicAdd(a + 2, s_r2);
        atomicAdd(a + 3, s_w2);
        atomicAdd(a + 4, s_rw);
        atomicAdd(acc_g + 0, s_pix);
    }
}

extern "C" void kernel_launch(void* const* d_in, const int* in_sizes, int n_in,
                              void* d_out, int out_size, void* d_ws, size_t ws_size,
                              hipStream_t stream) {
    const float* images = (const float*)d_in[0];
    const float* flows  = (const float*)d_in[1];
    float* acc_bc  = (float*)d_ws;             // 480*8 floats
    float* acc_g   = acc_bc + NB * NC * 8;     // 4 floats
    float* resized = (float*)d_ws + RES_OFF;   // 34.6 MB
    (void)hipMemsetAsync(d_ws, 0, (NB * NC * 8 + 4) * sizeof(float), stream);
    if (ws_size >= WS_NEED) {
        resize_kernel<<<RES_CNT / 256, 256, 0, stream>>>(images, resized);
        loss_main<<<NB * NC * SPLIT, 256, 0, stream>>>(resized, flows, acc_bc, acc_g);
    } else {
        loss_main_fb<<<NB * NC * 8, 256, 0, stream>>>(images, flows, acc_bc, acc_g);
    }
    smooth_kernel<<<1280, 256, 0, stream>>>(flows, acc_g);
    finalize<<<1, 512, 0, stream>>>(acc_bc, acc_g, (float*)d_out);
}

// Round 4
// 261.560 us; speedup vs baseline: 1.9777x; 1.0610x over previous
//
#include <hip/hip_runtime.h>

#define IH 256
#define IW 256
#define FH 128
#define FW 128
#define NB 16
#define ICH 33
#define NF 10
#define NC 30          // warped channels = NF*3
#define PL (FH * FW)   // 16384
#define ACC_FLOATS 3848                    // 480*8 acc_bc + 8 acc_g
#define RES_OFF 4096                       // floats: acc region + pad
#define RES_CNT (NB * ICH * PL)            // 8,650,752 floats
#define WS_NEED ((size_t)(RES_OFF + RES_CNT) * 4)

// fast exact charbonnier: (g^2 + 1e-6)^0.4, arg > 0 so hw log/exp safe (~1ulp)
__device__ __forceinline__ float charb(float g) {
    float t = fmaf(g, g, 1e-6f);
    return __builtin_amdgcn_exp2f(0.4f * __builtin_amdgcn_logf(t));
}

// ---- Kernel R: LDS-staged resize. One block = one plane row-pair (2x128 out px).
// Also zero-inits the accumulator region (block 0) -- stream-ordered before fat_kernel.
__global__ void __launch_bounds__(256) resize_kernel(const float* __restrict__ images,
                                                     float* __restrict__ resized,
                                                     float* __restrict__ acc)
{
    if (blockIdx.x == 0) {
        for (int i = threadIdx.x; i < ACC_FLOATS; i += 256) acc[i] = 0.f;
    }
    __shared__ float rows[4][256];
    const float s = (float)(255.0 / 127.0);
    int plane = blockIdx.x >> 6;           // 64 row-pairs per plane
    int j = blockIdx.x & 63;
    int h0 = 2 * j;
    int y0a = (int)((float)h0 * s);       if (y0a > IH - 2) y0a = IH - 2;
    int y0b = (int)((float)(h0 + 1) * s); if (y0b > IH - 2) y0b = IH - 2;
    int rowidx[4] = { y0a, y0a + 1, y0b, y0b + 1 };
    const float* pin = images + (size_t)plane * (IH * IW);
    // coalesced stage: each wave loads one 1KB input row as float4
    int r = threadIdx.x >> 6;
    int l = threadIdx.x & 63;
    const float4* srcv = (const float4*)(pin + rowidx[r] * IW);
    ((float4*)rows[r])[l] = srcv[l];
    __syncthreads();
    // compute: threads 0-127 -> out row h0, 128-255 -> out row h0+1
    int lr = threadIdx.x >> 7;
    int w = threadIdx.x & 127;
    int h = h0 + lr;
    float fy = (float)h * s;
    int y0 = lr ? y0b : y0a;
    float wy = fy - (float)y0;
    float fx = (float)w * s;
    int x0 = (int)fx; if (x0 > IW - 2) x0 = IW - 2;
    float wx = fx - (float)x0;
    float v00 = rows[2 * lr][x0],     v01 = rows[2 * lr][x0 + 1];
    float v10 = rows[2 * lr + 1][x0], v11 = rows[2 * lr + 1][x0 + 1];
    float r0 = v00 * (1.f - wy) + v10 * wy;     // y-interp first (matches reference)
    float r1 = v01 * (1.f - wy) + v11 * wy;
    resized[(size_t)plane * PL + h * FW + w] = r0 * (1.f - wx) + r1 * wx;
}

__device__ __forceinline__ float warp_sample(const float* __restrict__ src_plane,
                                             float gx, float gy) {
    float x0f = floorf(gx), y0f = floorf(gy);
    float wx = gx - x0f, wy = gy - y0f;
    int x0 = (int)x0f; x0 = min(max(x0, 0), FW - 1);
    int y0 = (int)y0f; y0 = min(max(y0, 0), FH - 1);
    int x1 = min(x0 + 1, FW - 1);
    int y1 = min(y0 + 1, FH - 1);
    const float* r0p = src_plane + y0 * FW;
    const float* r1p = src_plane + y1 * FW;
    float v00 = r0p[x0], v01 = r0p[x1];
    float v10 = r1p[x0], v11 = r1p[x1];
    float top = v00 * (1.f - wx) + v01 * wx;
    float bot = v10 * (1.f - wx) + v11 * wx;
    return top * (1.f - wy) + bot * wy;
}

// ---- Fat kernel: blocks [0,1920) = warp+SSIM+pixel-charb; [1920,3200) = smoothness
#define SPLIT 4
#define LOSS_BLOCKS (NB * NC * SPLIT)      // 1920
#define SMOOTH_BLOCKS 1280
#define PIX_PER_BLOCK (PL / SPLIT)         // 4096
__global__ void __launch_bounds__(256) fat_kernel(const float* __restrict__ resized,
                                                  const float* __restrict__ flows,
                                                  float* __restrict__ acc_bc,   // [480][8]
                                                  float* __restrict__ acc_g)    // [8]
{
    if (blockIdx.x < LOSS_BLOCKS) {
        int bc = blockIdx.x / SPLIT;
        int part = blockIdx.x % SPLIT;
        int b = bc / NC;
        int c = bc % NC;
        int f = c / 3;
        const float* ref_plane = resized + (size_t)(b * ICH + c) * PL;
        const float* src_plane = resized + (size_t)(b * ICH + 3 + c) * PL;
        const float* fx_plane  = flows + (size_t)(b * 2 * NF + 2 * f) * PL;
        const float* fy_plane  = fx_plane + PL;

        float s_ref = 0.f, s_w = 0.f, s_r2 = 0.f, s_w2 = 0.f, s_rw = 0.f, s_pix = 0.f;
        int base2 = part * (PIX_PER_BLOCK / 2);      // float2 index base
        for (int i = threadIdx.x; i < PIX_PER_BLOCK / 2; i += 256) {
            int pix2 = base2 + i;
            int pix = pix2 * 2;
            int h = pix >> 7;
            int w = pix & (FW - 1);
            float2 ref2 = ((const float2*)ref_plane)[pix2];
            float2 fx2  = ((const float2*)fx_plane)[pix2];
            float2 fy2  = ((const float2*)fy_plane)[pix2];

            float wv0 = warp_sample(src_plane, (float)w + fx2.x,       (float)h + fy2.x);
            float wv1 = warp_sample(src_plane, (float)(w + 1) + fx2.y, (float)h + fy2.y);

            s_ref += ref2.x + ref2.y;
            s_w   += wv0 + wv1;
            s_r2  += ref2.x * ref2.x + ref2.y * ref2.y;
            s_w2  += wv0 * wv0 + wv1 * wv1;
            s_rw  += ref2.x * wv0 + ref2.y * wv1;
            s_pix += charb(ref2.x - wv0) + charb(ref2.y - wv1);
        }
        for (int off = 32; off > 0; off >>= 1) {
            s_ref += __shfl_down(s_ref, off, 64);
            s_w   += __shfl_down(s_w, off, 64);
            s_r2  += __shfl_down(s_r2, off, 64);
            s_w2  += __shfl_down(s_w2, off, 64);
            s_rw  += __shfl_down(s_rw, off, 64);
            s_pix += __shfl_down(s_pix, off, 64);
        }
        __shared__ float sh[4][6];
        int wave = threadIdx.x >> 6;
        if ((threadIdx.x & 63) == 0) {
            sh[wave][0] = s_ref; sh[wave][1] = s_w; sh[wave][2] = s_r2;
            sh[wave][3] = s_w2;  sh[wave][4] = s_rw; sh[wave][5] = s_pix;
        }
        __syncthreads();
        if (threadIdx.x == 0) {
            float t0 = 0, t1 = 0, t2 = 0, t3 = 0, t4 = 0, t5 = 0;
            for (int v = 0; v < 4; v++) {
                t0 += sh[v][0]; t1 += sh[v][1]; t2 += sh[v][2];
                t3 += sh[v][3]; t4 += sh[v][4]; t5 += sh[v][5];
            }
            float* a = acc_bc + bc * 8;
            atomicAdd(a + 0, t0);
            atomicAdd(a + 1, t1);
            atomicAdd(a + 2, t2);
            atomicAdd(a + 3, t3);
            atomicAdd(a + 4, t4);
            atomicAdd(acc_g + 0, t5);
        }
    } else {
        // ---- smoothness: gradient along flow-index axis and H axis ----
        const int total = NB * NF * PL;
        float s = 0.f;
        for (int i = (blockIdx.x - LOSS_BLOCKS) * 256 + threadIdx.x; i < total;
             i += SMOOTH_BLOCKS * 256) {
            int w = i & (FW - 1);
            int h = (i >> 7) & (FH - 1);
            int f = (i >> 14) % NF;
            int b = i / (NF * PL);
            int pix = h * FW + w;
            const float* xp = flows + (size_t)(b * 2 * NF + 2 * f) * PL;
            const float* yp = xp + PL;

            float g1x, g1y;   // gradient along flow-channel axis (stride 2 planes)
            if (f == 0)           { g1x = xp[2 * PL + pix] - xp[pix];
                                    g1y = yp[2 * PL + pix] - yp[pix]; }
            else if (f == NF - 1) { g1x = xp[pix] - xp[pix - 2 * PL];
                                    g1y = yp[pix] - yp[pix - 2 * PL]; }
            else                  { g1x = 0.5f * (xp[2 * PL + pix] - xp[pix - 2 * PL]);
                                    g1y = 0.5f * (yp[2 * PL + pix] - yp[pix - 2 * PL]); }

            float g2x, g2y;   // gradient along H
            if (h == 0)           { g2x = xp[pix + FW] - xp[pix];
                                    g2y = yp[pix + FW] - yp[pix]; }
            else if (h == FH - 1) { g2x = xp[pix] - xp[pix - FW];
                                    g2y = yp[pix] - yp[pix - FW]; }
            else                  { g2x = 0.5f * (xp[pix + FW] - xp[pix - FW]);
                                    g2y = 0.5f * (yp[pix + FW] - yp[pix - FW]); }

            s += charb(g1x) + charb(g2x) + charb(g1y) + charb(g2y);
        }
        for (int off = 32; off > 0; off >>= 1) s += __shfl_down(s, off, 64);
        __shared__ float shs[4];
        int wave = threadIdx.x >> 6;
        if ((threadIdx.x & 63) == 0) shs[wave] = s;
        __syncthreads();
        if (threadIdx.x == 0)
            atomicAdd(acc_g + 2, shs[0] + shs[1] + shs[2] + shs[3]);
    }
}

// ---- Kernel C: per-(b,c) SSIM + final scalar ----
__global__ void __launch_bounds__(512) finalize(const float* __restrict__ acc_bc,
                                                const float* __restrict__ acc_g,
                                                float* __restrict__ out)
{
    __shared__ float sh[512];
    int tid = threadIdx.x;
    float ssim = 0.f;
    if (tid < NB * NC) {
        const float* a = acc_bc + tid * 8;
        const float N = (float)PL;
        float mu1 = a[0] / N, mu2 = a[1] / N;
        float var1 = (a[2] - a[0] * mu1) / (N - 1.f);
        float var2 = (a[3] - a[1] * mu2) / (N - 1.f);
        float s12 = a[4] / N - mu1 * mu2;
        float num = (2.f * mu1 * mu2 + 1e-4f) * (2.f * s12 + 1e-3f);
        float den = (mu1 * mu1 + mu2 * mu2 + 1e-4f) * (var1 + var2 + 1e-3f);
        ssim = num / den;
    }
    sh[tid] = ssim;
    __syncthreads();
    for (int off = 256; off > 0; off >>= 1) {
        if (tid < off) sh[tid] += sh[tid + off];
        __syncthreads();
    }
    if (tid == 0) {
        float pix    = acc_g[0] / (float)(NB * NC * PL);
        float smooth = acc_g[2] / (float)(NB * NF * PL);
        float sim    = sh[0] / (float)(NB * NC);
        out[0] = pix + 0.01f * smooth + sim;
    }
}

// ---- Fallback (no-workspace) path ----
__device__ __forceinline__ float resized_at(const float* __restrict__ plane, int Y, int X) {
    const float s = (float)(255.0 / 127.0);
    float fy = (float)Y * s;
    float fx = (float)X * s;
    int y0 = (int)fy; y0 = y0 > IH - 2 ? IH - 2 : y0;
    int x0 = (int)fx; x0 = x0 > IW - 2 ? IW - 2 : x0;
    float wy = fy - (float)y0;
    float wx = fx - (float)x0;
    const float* p0 = plane + y0 * IW + x0;
    float v00 = p0[0], v01 = p0[1];
    float v10 = p0[IW], v11 = p0[IW + 1];
    float r0 = v00 * (1.f - wy) + v10 * wy;
    float r1 = v01 * (1.f - wy) + v11 * wy;
    return r0 * (1.f - wx) + r1 * wx;
}

__global__ void __launch_bounds__(256) loss_main_fb(const float* __restrict__ images,
                                                    const float* __restrict__ flows,
                                                    float* __restrict__ acc_bc,
                                                    float* __restrict__ acc_g)
{
    int bc = blockIdx.x / 8;
    int part = blockIdx.x % 8;
    int b = bc / NC;
    int c = bc % NC;
    int f = c / 3;
    const float* ref_plane = images + (size_t)(b * ICH + c) * (IH * IW);
    const float* src_plane = images + (size_t)(b * ICH + 3 + c) * (IH * IW);
    const float* fx_plane  = flows + (size_t)(b * 2 * NF + 2 * f) * PL;
    const float* fy_plane  = fx_plane + PL;

    float s_ref = 0.f, s_w = 0.f, s_r2 = 0.f, s_w2 = 0.f, s_rw = 0.f, s_pix = 0.f;
    int base = part * (PL / 8);
    for (int i = threadIdx.x; i < PL / 8; i += 256) {
        int pix = base + i;
        int h = pix >> 7;
        int w = pix & (FW - 1);
        float ref = resized_at(ref_plane, h, w);
        float fxv = fx_plane[pix];
        float fyv = fy_plane[pix];
        float gx = (float)w + fxv;
        float gy = (float)h + fyv;
        float x0f = floorf(gx), y0f = floorf(gy);
        float wx = gx - x0f, wy = gy - y0f;
        int x0 = (int)x0f; x0 = min(max(x0, 0), FW - 1);
        int y0 = (int)y0f; y0 = min(max(y0, 0), FH - 1);
        int x1 = min(x0 + 1, FW - 1);
        int y1 = min(y0 + 1, FH - 1);
        float v00 = resized_at(src_plane, y0, x0);
        float v01 = resized_at(src_plane, y0, x1);
        float v10 = resized_at(src_plane, y1, x0);
        float v11 = resized_at(src_plane, y1, x1);
        float top = v00 * (1.f - wx) + v01 * wx;
        float bot = v10 * (1.f - wx) + v11 * wx;
        float wv = top * (1.f - wy) + bot * wy;
        s_ref += ref; s_w += wv;
        s_r2 += ref * ref; s_w2 += wv * wv; s_rw += ref * wv;
        s_pix += charb(ref - wv);
    }
    for (int off = 32; off > 0; off >>= 1) {
        s_ref += __shfl_down(s_ref, off, 64);
        s_w   += __shfl_down(s_w, off, 64);
        s_r2  += __shfl_down(s_r2, off, 64);
        s_w2  += __shfl_down(s_w2, off, 64);
        s_rw  += __shfl_down(s_rw, off, 64);
        s_pix += __shfl_down(s_pix, off, 64);
    }
    if ((threadIdx.x & 63) == 0) {
        float* a = acc_bc + bc * 8;
        atomicAdd(a + 0, s_ref);
        atomicAdd(a + 1, s_w);
        atomicAdd(a + 2, s_r2);
        atomicAdd(a + 3, s_w2);
        atomicAdd(a + 4, s_rw);
        atomicAdd(acc_g + 0, s_pix);
    }
}

__global__ void __launch_bounds__(256) smooth_fb(const float* __restrict__ flows,
                                                 float* __restrict__ acc_g)
{
    const int total = NB * NF * PL;
    float s = 0.f;
    for (int i = blockIdx.x * 256 + threadIdx.x; i < total; i += 1280 * 256) {
        int w = i & (FW - 1);
        int h = (i >> 7) & (FH - 1);
        int f = (i >> 14) % NF;
        int b = i / (NF * PL);
        int pix = h * FW + w;
        const float* xp = flows + (size_t)(b * 2 * NF + 2 * f) * PL;
        const float* yp = xp + PL;
        float g1x, g1y;
        if (f == 0)           { g1x = xp[2 * PL + pix] - xp[pix];
                                g1y = yp[2 * PL + pix] - yp[pix]; }
        else if (f == NF - 1) { g1x = xp[pix] - xp[pix - 2 * PL];
                                g1y = yp[pix] - yp[pix - 2 * PL]; }
        else                  { g1x = 0.5f * (xp[2 * PL + pix] - xp[pix - 2 * PL]);
                                g1y = 0.5f * (yp[2 * PL + pix] - yp[pix - 2 * PL]); }
        float g2x, g2y;
        if (h == 0)           { g2x = xp[pix + FW] - xp[pix];
                                g2y = yp[pix + FW] - yp[pix]; }
        else if (h == FH - 1) { g2x = xp[pix] - xp[pix - FW];
                                g2y = yp[pix] - yp[pix - FW]; }
        else                  { g2x = 0.5f * (xp[pix + FW] - xp[pix - FW]);
                                g2y = 0.5f * (yp[pix + FW] - yp[pix - FW]); }
        s += charb(g1x) + charb(g2x) + charb(g1y) + charb(g2y);
    }
    for (int off = 32; off > 0; off >>= 1) s += __shfl_down(s, off, 64);
    __shared__ float sh[4];
    int wave = threadIdx.x >> 6;
    if ((threadIdx.x & 63) == 0) sh[wave] = s;
    __syncthreads();
    if (threadIdx.x == 0)
        atomicAdd(acc_g + 2, sh[0] + sh[1] + sh[2] + sh[3]);
}

extern "C" void kernel_launch(void* const* d_in, const int* in_sizes, int n_in,
                              void* d_out, int out_size, void* d_ws, size_t ws_size,
                              hipStream_t stream) {
    const float* images = (const float*)d_in[0];
    const float* flows  = (const float*)d_in[1];
    float* acc_bc  = (float*)d_ws;             // 480*8 floats
    float* acc_g   = acc_bc + NB * NC * 8;     // 8 floats
    float* resized = (float*)d_ws + RES_OFF;   // 34.6 MB
    if (ws_size >= WS_NEED) {
        resize_kernel<<<NB * ICH * (FH / 2), 256, 0, stream>>>(images, resized, acc_bc);
        fat_kernel<<<LOSS_BLOCKS + SMOOTH_BLOCKS, 256, 0, stream>>>(resized, flows,
                                                                    acc_bc, acc_g);
    } else {
        (void)hipMemsetAsync(d_ws, 0, ACC_FLOATS * sizeof(float), stream);
        loss_main_fb<<<NB * NC * 8, 256, 0, stream>>>(images, flows, acc_bc, acc_g);
        smooth_fb<<<1280, 256, 0, stream>>>(flows, acc_g);
    }
    finalize<<<1, 512, 0, stream>>>(acc_bc, acc_g, (float*)d_out);
}